// Round 2
// baseline (429.319 us; speedup 1.0000x reference)
//
#include <hip/hip_runtime.h>
#include <stdint.h>

// ---------------------------------------------------------------------------
// Attention: out = softmax(Q K^T) V,  N=8, S=2048, E=512, fp32 in/out.
// R8 = R7 with the Q/K pre-pass ELIMINATED. Rationale: make_frags was ~115us
// (~50% of total) vs a 24us BW floor; its Q/K portion is pure data movement.
// attn_fused now gathers Q (prologue) and K (per tile) fragments directly
// from fp32 (two float4 loads per frag, same lane arithmetic the pre-pass
// used) and converts to fp16 in-register (8 v_cvt per frag). K is re-read
// from LLC (FETCH_SIZE showed 24.6MB HBM -> LLC serves the 50MB set).
// Pre-pass keeps ONLY the V transpose (512 blocks, ~49MB, ~10us).
// R7-proven structure unchanged: S -> V-prefetch -> b1 -> softmax -> b2 -> PV,
// setprio around MFMA clusters, barriers without vmcnt drain.
// ---------------------------------------------------------------------------

typedef __attribute__((ext_vector_type(8))) _Float16 half8;   // MFMA A/B frag
typedef __attribute__((ext_vector_type(2))) _Float16 half2;
typedef __attribute__((ext_vector_type(4))) float    floatx4; // MFMA C/D frag

#define NBATCH 8
#define SEQ    2048
#define EDIM   512
static constexpr size_t NE = (size_t)NBATCH * SEQ * EDIM;  // 8388608 elems/tensor

// Barrier WITHOUT vmcnt drain: LDS ordering only; global loads in flight stay
// in flight (their consumers get compiler-inserted vmcnt waits).
__device__ __forceinline__ void block_sync_lds() {
  asm volatile("s_waitcnt lgkmcnt(0)\n\ts_barrier" ::: "memory");
}

__device__ __forceinline__ half8 cvt8(float4 a, float4 b) {
  half8 h;
  h[0] = (_Float16)a.x; h[1] = (_Float16)a.y; h[2] = (_Float16)a.z; h[3] = (_Float16)a.w;
  h[4] = (_Float16)b.x; h[5] = (_Float16)b.y; h[6] = (_Float16)b.z; h[7] = (_Float16)b.w;
  return h;
}

// ---------------------------------------------------------------------------
// Fragment layout contract (A/B-frag 16x16x32): lane l holds
//   [dim16 = l&15][k = (l>>4)*8 + j].
// Q/K direct-gather: frag(row-tile r16, col-chunk c32) lane l elem j =
//   X[n, r16*16 + (l&15), c32*32 + (l>>4)*8 + j]  -> two float4 loads.
// V (pre-transposed): vf[((n*64 + kt)*32 + et)*512 + lane*8 + j]
//   (dim16 = e-col, k = krow within 32-tile).
// ---------------------------------------------------------------------------

// --- V-only pre-pass: 512 blocks (8 n x 64 kt), 32x512 f32 -> frag order fp16.
__global__ void make_vfrags(const float* __restrict__ v, _Float16* __restrict__ vf) {
  __shared__ float lds[32][260];
  const int tid = threadIdx.x;
  const int b2 = blockIdx.x;              // 8 n x 64 kt
  const int n = b2 >> 6, kt = b2 & 63;
  const float* src = v + ((size_t)n * SEQ + kt * 32) * EDIM;
  _Float16* dst = vf + ((size_t)(n * 64 + kt) * 32) * 512;
#pragma unroll
  for (int eh = 0; eh < 2; eh++) {
    if (eh) __syncthreads();
#pragma unroll
    for (int i = 0; i < 8; i++) {         // stage 32 rows x 256 f32
      int c = i * 256 + tid;
      int row = c >> 6, col4 = c & 63;
      float4 x = *reinterpret_cast<const float4*>(src + (size_t)row * EDIM + eh * 256 + col4 * 4);
      *reinterpret_cast<float4*>(&lds[row][col4 * 4]) = x;
    }
    __syncthreads();
#pragma unroll
    for (int i = 0; i < 4; i++) {         // emit frag chunks
      int fl = i * 256 + tid;
      int etl = fl >> 6, ln = fl & 63;
      int m15 = ln & 15, q4 = ln >> 4;
      int e_local = etl * 16 + m15;
      half8 h;
#pragma unroll
      for (int j = 0; j < 8; j++) h[j] = (_Float16)lds[q4 * 8 + j][e_local];
      *reinterpret_cast<half8*>(dst + ((size_t)eh * 1024 + fl) * 8) = h;
    }
  }
}

// ---------------------------------------------------------------------------
// Fused flash attention. Grid 512 = (n = blk&7, qt = blk>>3), 512 thr / 8 waves.
// BQ=32, BK=32, 64 K-tiles. Wave = (ks = w&1, es = w>>1):
//   S: both 16-q strips x its 16-krow half x 128-e quarter (K frags no-dup).
//   softmax: 32 rows x 16 thr, 2 cols each; 4-plane combine.
//   PV: wave owns 64-e slice (et = w*4..w*4+3).
// Per tile: K raw loads -> cvt -> S -> V prefetch -> s_part -> b1 -> softmax
//   -> b2 -> PV.
// LDS: 18432 + 2560 + 384 = 21376 B. __launch_bounds__(512,4) caps VGPR at
// 128 -> 2 blocks/CU. Peak live regs ~115 (qfr 32 + oacc 32 + K-raw 32).
// ---------------------------------------------------------------------------
__launch_bounds__(512, 4)
__global__ void attn_fused(const float* __restrict__ q, const float* __restrict__ k,
                           const _Float16* __restrict__ vf, float* __restrict__ out) {
  __shared__ float    s_part[4][32][36];   // 4 e-quarter partial scores
  __shared__ _Float16 p_lds[32][40];       // P fp16 (A-layout source)
  __shared__ float    m_lds[32], l_lds[32], a_lds[32];

  const int tid  = threadIdx.x;
  const int lane = tid & 63, w = tid >> 6;
  const int m15  = lane & 15, q4 = lane >> 4;
  const int n    = blockIdx.x & 7, qt = blockIdx.x >> 3;   // qt 0..63
  const int ks   = w & 1, es = w >> 1;

  if (tid < 32) { m_lds[tid] = -3.0e38f; l_lds[tid] = 0.0f; }

  // ---- Q fragments resident: direct fp32 gather + cvt. 32 VGPR persistent.
  half8 qfr[2][4];
  {
    // row = qt*32 + s*16 + m15, col = (es*4+i)*32 + q4*8
    const float* qb = q + ((size_t)n * SEQ + qt * 32 + m15) * EDIM + es * 128 + q4 * 8;
#pragma unroll
    for (int s = 0; s < 2; s++)
#pragma unroll
      for (int i = 0; i < 4; i++) {
        const float* src = qb + (size_t)s * 16 * EDIM + i * 32;
        float4 a = *reinterpret_cast<const float4*>(src);
        float4 b = *reinterpret_cast<const float4*>(src + 4);
        qfr[s][i] = cvt8(a, b);
      }
  }

  floatx4 oacc[2][4];                       // [strip][et_local], 32 regs (acc)
#pragma unroll
  for (int s = 0; s < 2; s++)
#pragma unroll
    for (int j = 0; j < 4; j++) oacc[s][j] = (floatx4){0.f, 0.f, 0.f, 0.f};

  // K float-index: row = t*32 + ks*16 + m15, col = es*128 + i*32 + q4*8
  uint32_t koff = ((uint32_t)(n * SEQ + ks * 16 + m15)) * EDIM + es * 128 + q4 * 8;
  uint32_t voff = ((uint32_t)(n * 64) * 32 + w * 4) * 512 + (uint32_t)lane * 8;

  block_sync_lds();                         // covers m/l init

  for (int t = 0; t < 64; t++) {
    // ---- K raw loads: all 8 float4 issued back-to-back (32 VGPR in flight),
    // then converted -> exposure ~ one LLC round-trip, same as old fp16 path.
    float4 ka[4], kb[4];
#pragma unroll
    for (int i = 0; i < 4; i++) {
      ka[i] = *reinterpret_cast<const float4*>(k + koff + (uint32_t)i * 32);
      kb[i] = *reinterpret_cast<const float4*>(k + koff + (uint32_t)i * 32 + 4);
    }
    koff += 32u * EDIM;                     // next 32 k-rows

    half8 kfr[4];
#pragma unroll
    for (int i = 0; i < 4; i++) kfr[i] = cvt8(ka[i], kb[i]);

    floatx4 sacc[2];
    sacc[0] = (floatx4){0.f, 0.f, 0.f, 0.f};
    sacc[1] = (floatx4){0.f, 0.f, 0.f, 0.f};
    __builtin_amdgcn_s_setprio(1);
#pragma unroll
    for (int i = 0; i < 4; i++) {
      sacc[0] = __builtin_amdgcn_mfma_f32_16x16x32_f16(qfr[0][i], kfr[i], sacc[0], 0, 0, 0);
      sacc[1] = __builtin_amdgcn_mfma_f32_16x16x32_f16(qfr[1][i], kfr[i], sacc[1], 0, 0, 0);
    }
    __builtin_amdgcn_s_setprio(0);

    // ---- V prefetch (this tile): issue NOW so the L2 latency hides under
    // b1 + softmax + b2. K-raw regs die at the cvt above; vfr born here.
    half8 vfr[4];
#pragma unroll
    for (int j = 0; j < 4; j++)
      vfr[j] = *reinterpret_cast<const half8*>(vf + voff + (uint32_t)j * 512);
    voff += 16384;                          // 32 et * 512

    // write partials (C-layout: row = q4*4+r, col = m15)
#pragma unroll
    for (int s = 0; s < 2; s++)
#pragma unroll
      for (int r = 0; r < 4; r++)
        s_part[es][s * 16 + q4 * 4 + r][ks * 16 + m15] = sacc[s][r];
    block_sync_lds();                       // b1

    // ---- softmax: 32 rows x 16 threads, 2 cols each
    {
      const int r = tid >> 4, sub = tid & 15, c = sub * 2;
      float svx = s_part[0][r][c],     svy = s_part[0][r][c + 1];
#pragma unroll
      for (int pl = 1; pl < 4; pl++) { svx += s_part[pl][r][c]; svy += s_part[pl][r][c + 1]; }
      float mx = fmaxf(svx, svy);
#pragma unroll
      for (int o = 1; o < 16; o <<= 1) mx = fmaxf(mx, __shfl_xor(mx, o));
      const float mo = m_lds[r];
      const float mn = fmaxf(mo, mx);
      const float px = __expf(svx - mn), py = __expf(svy - mn);
      float rs = px + py;
#pragma unroll
      for (int o = 1; o < 16; o <<= 1) rs += __shfl_xor(rs, o);
      if (sub == 0) {
        const float al = __expf(mo - mn);
        a_lds[r] = al; m_lds[r] = mn; l_lds[r] = l_lds[r] * al + rs;
      }
      half2 ph; ph[0] = (_Float16)px; ph[1] = (_Float16)py;
      *reinterpret_cast<half2*>(&p_lds[r][c]) = ph;
    }
    block_sync_lds();                       // b2

    // ---- PV phase: P A-frags from LDS, rescale, MFMA (vfr already in flight)
    half8 pfr[2];
    pfr[0] = *reinterpret_cast<const half8*>(&p_lds[m15][q4 * 8]);
    pfr[1] = *reinterpret_cast<const half8*>(&p_lds[16 + m15][q4 * 8]);
    {
      floatx4 al0 = *reinterpret_cast<floatx4*>(&a_lds[q4 * 4]);
      floatx4 al1 = *reinterpret_cast<floatx4*>(&a_lds[16 + q4 * 4]);
#pragma unroll
      for (int j = 0; j < 4; j++) { oacc[0][j] *= al0; oacc[1][j] *= al1; }
    }
    __builtin_amdgcn_s_setprio(1);
#pragma unroll
    for (int j = 0; j < 4; j++) {
      oacc[0][j] = __builtin_amdgcn_mfma_f32_16x16x32_f16(pfr[0], vfr[j], oacc[0][j], 0, 0, 0);
      oacc[1][j] = __builtin_amdgcn_mfma_f32_16x16x32_f16(pfr[1], vfr[j], oacc[1][j], 0, 0, 0);
    }
    __builtin_amdgcn_s_setprio(0);
  }

  // ---- epilogue: divide by l, store fp32 (l_lds final after last b2)
  const int q0 = qt * 32;
#pragma unroll
  for (int s = 0; s < 2; s++) {
    floatx4 lv = *reinterpret_cast<floatx4*>(&l_lds[s * 16 + q4 * 4]);
#pragma unroll
    for (int j = 0; j < 4; j++) {
      const int col = (w * 4 + j) * 16 + m15;
#pragma unroll
      for (int r = 0; r < 4; r++) {
        const int row = s * 16 + q4 * 4 + r;
        out[((size_t)n * SEQ + q0 + row) * EDIM + col] = oacc[s][j][r] / lv[r];
      }
    }
  }
}

// ---------------------------------------------------------------------------
// Fallback (ws too small): fp32 VALU attention, one block per query row.
// ---------------------------------------------------------------------------
__global__ void attn_fallback(const float* __restrict__ q, const float* __restrict__ k,
                              const float* __restrict__ v, float* __restrict__ out) {
  __shared__ float qrow[EDIM];
  __shared__ float sc[SEQ];
  __shared__ float red[16];
  const int tid = threadIdx.x;                    // 256
  const int n = blockIdx.x >> 11, qi = blockIdx.x & 2047;
  const int wv = tid >> 6, ln = tid & 63;
  const float* qp = q + ((size_t)n * SEQ + qi) * EDIM;
  for (int e = tid; e < EDIM; e += 256) qrow[e] = qp[e];
  __syncthreads();
  for (int kk = wv; kk < SEQ; kk += 4) {
    const float* kp = k + ((size_t)n * SEQ + kk) * EDIM;
    float s = 0.f;
    for (int e = ln; e < EDIM; e += 64) s = fmaf(qrow[e], kp[e], s);
    for (int o = 32; o > 0; o >>= 1) s += __shfl_down(s, o);
    if (ln == 0) sc[kk] = s;
  }
  __syncthreads();
  float mx = -3.0e38f;
  for (int kk = tid; kk < SEQ; kk += 256) mx = fmaxf(mx, sc[kk]);
  for (int o = 32; o > 0; o >>= 1) mx = fmaxf(mx, __shfl_down(mx, o));
  if (ln == 0) red[wv] = mx;
  __syncthreads();
  if (tid == 0) {
    float m2 = red[0];
    for (int i = 1; i < 4; i++) m2 = fmaxf(m2, red[i]);
    red[8] = m2;
  }
  __syncthreads();
  const float m = red[8];
  float ls = 0.f;
  for (int kk = tid; kk < SEQ; kk += 256) { float p = __expf(sc[kk] - m); sc[kk] = p; ls += p; }
  for (int o = 32; o > 0; o >>= 1) ls += __shfl_down(ls, o);
  if (ln == 0) red[wv] = ls;
  __syncthreads();
  if (tid == 0) { red[9] = red[0] + red[1] + red[2] + red[3]; }
  __syncthreads();
  const float linv = 1.f / red[9];
  for (int e = tid; e < EDIM; e += 256) {
    float acc = 0.f;
    const float* vp = v + ((size_t)n * SEQ) * EDIM + e;
    for (int kk = 0; kk < SEQ; kk++) acc = fmaf(sc[kk], vp[(size_t)kk * EDIM], acc);
    out[((size_t)n * SEQ + qi) * EDIM + e] = acc * linv;
  }
}

extern "C" void kernel_launch(void* const* d_in, const int* in_sizes, int n_in,
                              void* d_out, int out_size, void* d_ws, size_t ws_size,
                              hipStream_t stream) {
  const float* q = (const float*)d_in[0];
  const float* k = (const float*)d_in[1];
  const float* v = (const float*)d_in[2];
  float* out = (float*)d_out;
  const size_t need = NE * sizeof(_Float16);   // 16.8 MB (V frags only)
  if (ws_size >= need) {
    _Float16* vf = (_Float16*)d_ws;
    make_vfrags<<<512, 256, 0, stream>>>(v, vf);
    attn_fused<<<512, 512, 0, stream>>>(q, k, vf, out);
  } else {
    attn_fallback<<<16384, 256, 0, stream>>>(q, k, v, out);
  }
}

// Round 3
// 239.077 us; speedup vs baseline: 1.7957x; 1.7957x over previous
//
#include <hip/hip_runtime.h>
#include <stdint.h>

// ---------------------------------------------------------------------------
// Attention: out = softmax(Q K^T) V,  N=8, S=2048, E=512, fp32 in/out.
// R9 = attn_fused reverted EXACTLY to R7 (proven 117.9us) + pre-pass rewritten
// with LDS staging for Q/K (the R7 pre-pass was ~115us because its Q/K gather
// read fp32 at lane stride 2048B -> 32 scattered lines per instruction; R8
// proved that pattern costs ~3x when moved inline). Now all three tensors
// stage 32x256 f32 tiles coalesced into LDS, emit frag chunks from LDS
// (row-contiguous b128 reads for Q/K, column reads for V), and store
// wave-contiguous 1KB half8 chunks.
// ---------------------------------------------------------------------------

typedef __attribute__((ext_vector_type(8))) _Float16 half8;   // MFMA A/B frag
typedef __attribute__((ext_vector_type(2))) _Float16 half2;
typedef __attribute__((ext_vector_type(4))) float    floatx4; // MFMA C/D frag

#define NBATCH 8
#define SEQ    2048
#define EDIM   512
static constexpr size_t NE = (size_t)NBATCH * SEQ * EDIM;  // 8388608 elems/tensor

// Barrier WITHOUT vmcnt drain: LDS ordering only; global loads in flight stay
// in flight (their consumers get compiler-inserted vmcnt waits).
__device__ __forceinline__ void block_sync_lds() {
  asm volatile("s_waitcnt lgkmcnt(0)\n\ts_barrier" ::: "memory");
}

__device__ __forceinline__ half8 cvt8(float4 a, float4 b) {
  half8 h;
  h[0] = (_Float16)a.x; h[1] = (_Float16)a.y; h[2] = (_Float16)a.z; h[3] = (_Float16)a.w;
  h[4] = (_Float16)b.x; h[5] = (_Float16)b.y; h[6] = (_Float16)b.z; h[7] = (_Float16)b.w;
  return h;
}

// ---------------------------------------------------------------------------
// Fragment layout contract (A/B-frag 16x16x32): lane l holds
//   [dim16 = l&15][k = (l>>4)*8 + j].
//  Q/K: xf[((n*128 + rt)*16 + est)*512 + lane*8 + j]   (rt = row>>4, est = e>>5)
//  V:   vf[((n*64 + kt)*32 + et)*512 + lane*8 + j]     (kt = krow>>5, et = e>>4,
//        dim16 = e-col, k = krow within 32-tile)
// ---------------------------------------------------------------------------

// --- pre-pass: 1536 blocks = 3 segments x 8 n x 64 row-tiles (32 rows each).
// All segments: stage 32 rows x 256 f32 coalesced in LDS, emit from LDS.
__global__ void make_frags(const float* __restrict__ q, const float* __restrict__ k,
                           const float* __restrict__ v,
                           _Float16* __restrict__ qf, _Float16* __restrict__ kf,
                           _Float16* __restrict__ vf) {
  __shared__ float lds[32][260];
  const int tid = threadIdx.x;
  const int seg = blockIdx.x >> 9;        // 0=Q, 1=K, 2=V
  const int b   = blockIdx.x & 511;       // 8 n x 64 kt
  const int n = b >> 6, kt = b & 63;
  const float* src = (seg == 0 ? q : seg == 1 ? k : v) + ((size_t)n * SEQ + kt * 32) * EDIM;

  if (seg < 2) {
    // Q/K: frag chunk (rt, est) lane l elem j = X[row = rt*16 + (l&15),
    //      col = est*32 + (l>>4)*8 + j]. Row-contiguous in LDS -> b128 reads.
    _Float16* dst = (seg == 0 ? qf : kf) + ((size_t)(n * 128 + kt * 2) * 16) * 512;
#pragma unroll
    for (int eh = 0; eh < 2; eh++) {
      if (eh) __syncthreads();
#pragma unroll
      for (int i = 0; i < 8; i++) {       // stage 32 rows x 256 f32 (coalesced)
        int c = i * 256 + tid;
        int row = c >> 6, col4 = c & 63;
        float4 x = *reinterpret_cast<const float4*>(src + (size_t)row * EDIM + eh * 256 + col4 * 4);
        *reinterpret_cast<float4*>(&lds[row][col4 * 4]) = x;
      }
      __syncthreads();
#pragma unroll
      for (int i = 0; i < 4; i++) {       // emit 1024 half8 chunks / half
        int fl = i * 256 + tid;
        int lane = fl & 63, idx = fl >> 6;        // idx 0..15
        int est_l = idx & 7, rt_l = idx >> 3;     // est_l 0..7, rt_l 0..1
        int m15 = lane & 15, q4 = lane >> 4;
        const float* p = &lds[rt_l * 16 + m15][est_l * 32 + q4 * 8];
        float4 a = *reinterpret_cast<const float4*>(p);
        float4 bb = *reinterpret_cast<const float4*>(p + 4);
        // dst: (rt_l*16 + eh*8 + est_l)*512 + lane*8 — wave-contiguous 1KB store
        *reinterpret_cast<half8*>(dst + ((size_t)(rt_l * 16 + eh * 8 + est_l)) * 512 + lane * 8) =
            cvt8(a, bb);
      }
    }
  } else {
    // V: transpose — frag chunk et lane l elem j = V[krow = kt*32 + (l>>4)*8+j,
    //    e = et*16 + (l&15)]. Column reads from LDS.
    _Float16* dst = vf + ((size_t)(n * 64 + kt) * 32) * 512;
#pragma unroll
    for (int eh = 0; eh < 2; eh++) {
      if (eh) __syncthreads();
#pragma unroll
      for (int i = 0; i < 8; i++) {       // stage 32 rows x 256 f32
        int c = i * 256 + tid;
        int row = c >> 6, col4 = c & 63;
        float4 x = *reinterpret_cast<const float4*>(src + (size_t)row * EDIM + eh * 256 + col4 * 4);
        *reinterpret_cast<float4*>(&lds[row][col4 * 4]) = x;
      }
      __syncthreads();
#pragma unroll
      for (int i = 0; i < 4; i++) {       // emit frag chunks
        int fl = i * 256 + tid;
        int etl = fl >> 6, ln = fl & 63;
        int m15 = ln & 15, q4 = ln >> 4;
        int e_local = etl * 16 + m15;
        half8 h;
#pragma unroll
        for (int j = 0; j < 8; j++) h[j] = (_Float16)lds[q4 * 8 + j][e_local];
        *reinterpret_cast<half8*>(dst + ((size_t)eh * 1024 + fl) * 8) = h;
      }
    }
  }
}

// ---------------------------------------------------------------------------
// Fused flash attention — EXACT R7 structure (proven 117.9us).
// Grid 512 = (n = blk&7, qt = blk>>3), 512 thr / 8 waves.
// BQ=32, BK=32, 64 K-tiles. Wave = (ks = w&1, es = w>>1):
//   S: both 16-q strips x its 16-krow half x 128-e quarter (K frags no-dup).
//   softmax: 32 rows x 16 thr, 2 cols each; 4-plane combine.
//   PV: wave owns 64-e slice (et = w*4..w*4+3).
// Per tile: S -> (V prefetch) -> s_part -> b1 -> softmax -> b2 -> PV.
// LDS: 18432 + 2560 + 384 = 21376 B. __launch_bounds__(512,4) caps VGPR at
// 128 -> 2 blocks/CU; transient K/V frag loads keep peak live regs ~110.
// ---------------------------------------------------------------------------
__launch_bounds__(512, 4)
__global__ void attn_fused(const _Float16* __restrict__ qf, const _Float16* __restrict__ kf,
                           const _Float16* __restrict__ vf, float* __restrict__ out) {
  __shared__ float    s_part[4][32][36];   // 4 e-quarter partial scores
  __shared__ _Float16 p_lds[32][40];       // P fp16 (A-layout source)
  __shared__ float    m_lds[32], l_lds[32], a_lds[32];

  const int tid  = threadIdx.x;
  const int lane = tid & 63, w = tid >> 6;
  const int m15  = lane & 15, q4 = lane >> 4;
  const int n    = blockIdx.x & 7, qt = blockIdx.x >> 3;   // qt 0..63
  const int ks   = w & 1, es = w >> 1;

  if (tid < 32) { m_lds[tid] = -3.0e38f; l_lds[tid] = 0.0f; }

  // ---- Q fragments resident: 2 strips x 4 est (this wave's e-quarter). 32 VGPR.
  half8 qfr[2][4];
  {
    const uint32_t qbase = ((uint32_t)(n * 128 + qt * 2) * 16 + es * 4) * 512 + (uint32_t)lane * 8;
#pragma unroll
    for (int s = 0; s < 2; s++)
#pragma unroll
      for (int i = 0; i < 4; i++)
        qfr[s][i] = *reinterpret_cast<const half8*>(qf + qbase + (uint32_t)(s * 16 + i) * 512);
  }

  floatx4 oacc[2][4];                       // [strip][et_local], 32 regs (acc)
#pragma unroll
  for (int s = 0; s < 2; s++)
#pragma unroll
    for (int j = 0; j < 4; j++) oacc[s][j] = (floatx4){0.f, 0.f, 0.f, 0.f};

  uint32_t koff = ((uint32_t)(n * 128 + ks) * 16 + es * 4) * 512 + (uint32_t)lane * 8;
  uint32_t voff = ((uint32_t)(n * 64) * 32 + w * 4) * 512 + (uint32_t)lane * 8;

  block_sync_lds();                         // covers m/l init

  for (int t = 0; t < 64; t++) {
    // ---- S phase: K frags transient, direct global->reg (1KB coalesced each)
    half8 kfr[4];
#pragma unroll
    for (int i = 0; i < 4; i++)
      kfr[i] = *reinterpret_cast<const half8*>(kf + koff + (uint32_t)i * 512);
    koff += 16384;                          // 2 rt * 16 est * 512

    floatx4 sacc[2];
    sacc[0] = (floatx4){0.f, 0.f, 0.f, 0.f};
    sacc[1] = (floatx4){0.f, 0.f, 0.f, 0.f};
    __builtin_amdgcn_s_setprio(1);
#pragma unroll
    for (int i = 0; i < 4; i++) {
      sacc[0] = __builtin_amdgcn_mfma_f32_16x16x32_f16(qfr[0][i], kfr[i], sacc[0], 0, 0, 0);
      sacc[1] = __builtin_amdgcn_mfma_f32_16x16x32_f16(qfr[1][i], kfr[i], sacc[1], 0, 0, 0);
    }
    __builtin_amdgcn_s_setprio(0);

    // ---- V prefetch (this tile): independent of LDS/barriers; issue NOW so
    // the L2 latency hides under b1 + softmax + b2. kfr dies at the MFMAs
    // above, vfr is born here -> no peak-VGPR increase.
    half8 vfr[4];
#pragma unroll
    for (int j = 0; j < 4; j++)
      vfr[j] = *reinterpret_cast<const half8*>(vf + voff + (uint32_t)j * 512);
    voff += 16384;                          // 32 et * 512

    // write partials (C-layout: row = q4*4+r, col = m15)
#pragma unroll
    for (int s = 0; s < 2; s++)
#pragma unroll
      for (int r = 0; r < 4; r++)
        s_part[es][s * 16 + q4 * 4 + r][ks * 16 + m15] = sacc[s][r];
    block_sync_lds();                       // b1

    // ---- softmax: 32 rows x 16 threads, 2 cols each
    {
      const int r = tid >> 4, sub = tid & 15, c = sub * 2;
      float svx = s_part[0][r][c],     svy = s_part[0][r][c + 1];
#pragma unroll
      for (int pl = 1; pl < 4; pl++) { svx += s_part[pl][r][c]; svy += s_part[pl][r][c + 1]; }
      float mx = fmaxf(svx, svy);
#pragma unroll
      for (int o = 1; o < 16; o <<= 1) mx = fmaxf(mx, __shfl_xor(mx, o));
      const float mo = m_lds[r];
      const float mn = fmaxf(mo, mx);
      const float px = __expf(svx - mn), py = __expf(svy - mn);
      float rs = px + py;
#pragma unroll
      for (int o = 1; o < 16; o <<= 1) rs += __shfl_xor(rs, o);
      if (sub == 0) {
        const float al = __expf(mo - mn);
        a_lds[r] = al; m_lds[r] = mn; l_lds[r] = l_lds[r] * al + rs;
      }
      half2 ph; ph[0] = (_Float16)px; ph[1] = (_Float16)py;
      *reinterpret_cast<half2*>(&p_lds[r][c]) = ph;
    }
    block_sync_lds();                       // b2

    // ---- PV phase: P A-frags from LDS, rescale, MFMA (vfr already in flight)
    half8 pfr[2];
    pfr[0] = *reinterpret_cast<const half8*>(&p_lds[m15][q4 * 8]);
    pfr[1] = *reinterpret_cast<const half8*>(&p_lds[16 + m15][q4 * 8]);
    {
      floatx4 al0 = *reinterpret_cast<floatx4*>(&a_lds[q4 * 4]);
      floatx4 al1 = *reinterpret_cast<floatx4*>(&a_lds[16 + q4 * 4]);
#pragma unroll
      for (int j = 0; j < 4; j++) { oacc[0][j] *= al0; oacc[1][j] *= al1; }
    }
    __builtin_amdgcn_s_setprio(1);
#pragma unroll
    for (int j = 0; j < 4; j++) {
      oacc[0][j] = __builtin_amdgcn_mfma_f32_16x16x32_f16(pfr[0], vfr[j], oacc[0][j], 0, 0, 0);
      oacc[1][j] = __builtin_amdgcn_mfma_f32_16x16x32_f16(pfr[1], vfr[j], oacc[1][j], 0, 0, 0);
    }
    __builtin_amdgcn_s_setprio(0);
  }

  // ---- epilogue: divide by l, store fp32 (l_lds final after last b2)
  const int q0 = qt * 32;
#pragma unroll
  for (int s = 0; s < 2; s++) {
    floatx4 lv = *reinterpret_cast<floatx4*>(&l_lds[s * 16 + q4 * 4]);
#pragma unroll
    for (int j = 0; j < 4; j++) {
      const int col = (w * 4 + j) * 16 + m15;
#pragma unroll
      for (int r = 0; r < 4; r++) {
        const int row = s * 16 + q4 * 4 + r;
        out[((size_t)n * SEQ + q0 + row) * EDIM + col] = oacc[s][j][r] / lv[r];
      }
    }
  }
}

// ---------------------------------------------------------------------------
// Fallback (ws too small): fp32 VALU attention, one block per query row.
// ---------------------------------------------------------------------------
__global__ void attn_fallback(const float* __restrict__ q, const float* __restrict__ k,
                              const float* __restrict__ v, float* __restrict__ out) {
  __shared__ float qrow[EDIM];
  __shared__ float sc[SEQ];
  __shared__ float red[16];
  const int tid = threadIdx.x;                    // 256
  const int n = blockIdx.x >> 11, qi = blockIdx.x & 2047;
  const int wv = tid >> 6, ln = tid & 63;
  const float* qp = q + ((size_t)n * SEQ + qi) * EDIM;
  for (int e = tid; e < EDIM; e += 256) qrow[e] = qp[e];
  __syncthreads();
  for (int kk = wv; kk < SEQ; kk += 4) {
    const float* kp = k + ((size_t)n * SEQ + kk) * EDIM;
    float s = 0.f;
    for (int e = ln; e < EDIM; e += 64) s = fmaf(qrow[e], kp[e], s);
    for (int o = 32; o > 0; o >>= 1) s += __shfl_down(s, o);
    if (ln == 0) sc[kk] = s;
  }
  __syncthreads();
  float mx = -3.0e38f;
  for (int kk = tid; kk < SEQ; kk += 256) mx = fmaxf(mx, sc[kk]);
  for (int o = 32; o > 0; o >>= 1) mx = fmaxf(mx, __shfl_down(mx, o));
  if (ln == 0) red[wv] = mx;
  __syncthreads();
  if (tid == 0) {
    float m2 = red[0];
    for (int i = 1; i < 4; i++) m2 = fmaxf(m2, red[i]);
    red[8] = m2;
  }
  __syncthreads();
  const float m = red[8];
  float ls = 0.f;
  for (int kk = tid; kk < SEQ; kk += 256) { float p = __expf(sc[kk] - m); sc[kk] = p; ls += p; }
  for (int o = 32; o > 0; o >>= 1) ls += __shfl_down(ls, o);
  if (ln == 0) red[wv] = ls;
  __syncthreads();
  if (tid == 0) { red[9] = red[0] + red[1] + red[2] + red[3]; }
  __syncthreads();
  const float linv = 1.f / red[9];
  for (int e = tid; e < EDIM; e += 256) {
    float acc = 0.f;
    const float* vp = v + ((size_t)n * SEQ) * EDIM + e;
    for (int kk = 0; kk < SEQ; kk++) acc = fmaf(sc[kk], vp[(size_t)kk * EDIM], acc);
    out[((size_t)n * SEQ + qi) * EDIM + e] = acc * linv;
  }
}

extern "C" void kernel_launch(void* const* d_in, const int* in_sizes, int n_in,
                              void* d_out, int out_size, void* d_ws, size_t ws_size,
                              hipStream_t stream) {
  const float* q = (const float*)d_in[0];
  const float* k = (const float*)d_in[1];
  const float* v = (const float*)d_in[2];
  float* out = (float*)d_out;
  const size_t need = 3 * NE * sizeof(_Float16);   // 50.3 MB
  if (ws_size >= need) {
    _Float16* qf = (_Float16*)d_ws;
    _Float16* kf = qf + NE;
    _Float16* vf = kf + NE;
    make_frags<<<1536, 256, 0, stream>>>(q, k, v, qf, kf, vf);
    attn_fused<<<512, 512, 0, stream>>>(qf, kf, vf, out);
  } else {
    attn_fallback<<<16384, 256, 0, stream>>>(q, k, v, out);
  }
}

// Round 4
// 234.856 us; speedup vs baseline: 1.8280x; 1.0180x over previous
//
#include <hip/hip_runtime.h>
#include <stdint.h>

// ---------------------------------------------------------------------------
// Attention: out = softmax(Q K^T) V,  N=8, S=2048, E=512, fp32 in/out.
// R10 = R9 + (a) K software-pipelined one tile ahead (same lever that won R7
// for V: the asm barrier's "memory" clobber pins loads issued after it, so
// un-prefetched K ate a full LLC round-trip serially every tile), and
// (b) Q pre-pass segment eliminated — Q rows are block-partitioned (qt), so
// attn_fused gathers Q fp32 directly in the prologue (one-time cost; code
// path numerically verified in R8). Pre-pass is now K+V only (1024 blocks).
// Hazard structure unchanged: S -> prefetch(Knext,V) -> b1 -> softmax -> b2
// -> PV. setprio around MFMA clusters. Barriers never drain vmcnt.
// ---------------------------------------------------------------------------

typedef __attribute__((ext_vector_type(8))) _Float16 half8;   // MFMA A/B frag
typedef __attribute__((ext_vector_type(2))) _Float16 half2;
typedef __attribute__((ext_vector_type(4))) float    floatx4; // MFMA C/D frag

#define NBATCH 8
#define SEQ    2048
#define EDIM   512
static constexpr size_t NE = (size_t)NBATCH * SEQ * EDIM;  // 8388608 elems/tensor

// Barrier WITHOUT vmcnt drain: LDS ordering only; global loads in flight stay
// in flight (their consumers get compiler-inserted vmcnt waits).
__device__ __forceinline__ void block_sync_lds() {
  asm volatile("s_waitcnt lgkmcnt(0)\n\ts_barrier" ::: "memory");
}

__device__ __forceinline__ half8 cvt8(float4 a, float4 b) {
  half8 h;
  h[0] = (_Float16)a.x; h[1] = (_Float16)a.y; h[2] = (_Float16)a.z; h[3] = (_Float16)a.w;
  h[4] = (_Float16)b.x; h[5] = (_Float16)b.y; h[6] = (_Float16)b.z; h[7] = (_Float16)b.w;
  return h;
}

// ---------------------------------------------------------------------------
// Fragment layout contract (A/B-frag 16x16x32): lane l holds
//   [dim16 = l&15][k = (l>>4)*8 + j].
//  K: kf[((n*128 + rt)*16 + est)*512 + lane*8 + j]   (rt = row>>4, est = e>>5)
//  V: vf[((n*64 + kt)*32 + et)*512 + lane*8 + j]     (kt = krow>>5, et = e>>4,
//        dim16 = e-col, k = krow within 32-tile)
// ---------------------------------------------------------------------------

// --- pre-pass: 1024 blocks = 2 segments (K,V) x 8 n x 64 row-tiles.
__global__ void make_frags(const float* __restrict__ k, const float* __restrict__ v,
                           _Float16* __restrict__ kf, _Float16* __restrict__ vf) {
  __shared__ float lds[32][260];
  const int tid = threadIdx.x;
  const int seg = blockIdx.x >> 9;        // 0=K, 1=V
  const int b   = blockIdx.x & 511;       // 8 n x 64 kt
  const int n = b >> 6, kt = b & 63;
  const float* src = (seg == 0 ? k : v) + ((size_t)n * SEQ + kt * 32) * EDIM;

  if (seg == 0) {
    // K: frag chunk (rt, est) lane l elem j = X[row = rt*16 + (l&15),
    //    col = est*32 + (l>>4)*8 + j]. Row-contiguous in LDS -> b128 reads.
    _Float16* dst = kf + ((size_t)(n * 128 + kt * 2) * 16) * 512;
#pragma unroll
    for (int eh = 0; eh < 2; eh++) {
      if (eh) __syncthreads();
#pragma unroll
      for (int i = 0; i < 8; i++) {       // stage 32 rows x 256 f32 (coalesced)
        int c = i * 256 + tid;
        int row = c >> 6, col4 = c & 63;
        float4 x = *reinterpret_cast<const float4*>(src + (size_t)row * EDIM + eh * 256 + col4 * 4);
        *reinterpret_cast<float4*>(&lds[row][col4 * 4]) = x;
      }
      __syncthreads();
#pragma unroll
      for (int i = 0; i < 4; i++) {       // emit 1024 half8 chunks / half
        int fl = i * 256 + tid;
        int lane = fl & 63, idx = fl >> 6;        // idx 0..15
        int est_l = idx & 7, rt_l = idx >> 3;     // est_l 0..7, rt_l 0..1
        int m15 = lane & 15, q4 = lane >> 4;
        const float* p = &lds[rt_l * 16 + m15][est_l * 32 + q4 * 8];
        float4 a = *reinterpret_cast<const float4*>(p);
        float4 bb = *reinterpret_cast<const float4*>(p + 4);
        *reinterpret_cast<half8*>(dst + ((size_t)(rt_l * 16 + eh * 8 + est_l)) * 512 + lane * 8) =
            cvt8(a, bb);
      }
    }
  } else {
    // V: transpose — frag chunk et lane l elem j = V[krow = kt*32 + (l>>4)*8+j,
    //    e = et*16 + (l&15)]. Column reads from LDS.
    _Float16* dst = vf + ((size_t)(n * 64 + kt) * 32) * 512;
#pragma unroll
    for (int eh = 0; eh < 2; eh++) {
      if (eh) __syncthreads();
#pragma unroll
      for (int i = 0; i < 8; i++) {       // stage 32 rows x 256 f32
        int c = i * 256 + tid;
        int row = c >> 6, col4 = c & 63;
        float4 x = *reinterpret_cast<const float4*>(src + (size_t)row * EDIM + eh * 256 + col4 * 4);
        *reinterpret_cast<float4*>(&lds[row][col4 * 4]) = x;
      }
      __syncthreads();
#pragma unroll
      for (int i = 0; i < 4; i++) {       // emit frag chunks
        int fl = i * 256 + tid;
        int etl = fl >> 6, ln = fl & 63;
        int m15 = ln & 15, q4 = ln >> 4;
        int e_local = etl * 16 + m15;
        half8 h;
#pragma unroll
        for (int j = 0; j < 8; j++) h[j] = (_Float16)lds[q4 * 8 + j][e_local];
        *reinterpret_cast<half8*>(dst + ((size_t)eh * 1024 + fl) * 8) = h;
      }
    }
  }
}

// ---------------------------------------------------------------------------
// Fused flash attention. Grid 512 = (n = blk&7, qt = blk>>3), 512 thr / 8 waves.
// BQ=32, BK=32, 64 K-tiles. Wave = (ks = w&1, es = w>>1):
//   S: both 16-q strips x its 16-krow half x 128-e quarter (K frags no-dup).
//   softmax: 32 rows x 16 thr, 2 cols each; 4-plane combine.
//   PV: wave owns 64-e slice (et = w*4..w*4+3).
// Per tile: S(kcur) -> prefetch(knxt, vfr) -> s_part -> b1 -> softmax -> b2
//   -> PV -> kcur=knxt. K latency hides under b1+softmax+b2+PV of prev tile.
// LDS: 18432 + 2560 + 384 = 21376 B. __launch_bounds__(512,4) caps VGPR at
// 128 -> 2 blocks/CU. Peak live ~: qfr32 + oacc32 + knxt16 + vfr16 + misc.
// ---------------------------------------------------------------------------
__launch_bounds__(512, 4)
__global__ void attn_fused(const float* __restrict__ q, const _Float16* __restrict__ kf,
                           const _Float16* __restrict__ vf, float* __restrict__ out) {
  __shared__ float    s_part[4][32][36];   // 4 e-quarter partial scores
  __shared__ _Float16 p_lds[32][40];       // P fp16 (A-layout source)
  __shared__ float    m_lds[32], l_lds[32], a_lds[32];

  const int tid  = threadIdx.x;
  const int lane = tid & 63, w = tid >> 6;
  const int m15  = lane & 15, q4 = lane >> 4;
  const int n    = blockIdx.x & 7, qt = blockIdx.x >> 3;   // qt 0..63
  const int ks   = w & 1, es = w >> 1;

  if (tid < 32) { m_lds[tid] = -3.0e38f; l_lds[tid] = 0.0f; }

  // ---- Q fragments: direct fp32 gather + cvt (one-time; R8-verified path).
  // row = qt*32 + s*16 + m15, col = (es*4+i)*32 + q4*8. 32 VGPR persistent.
  half8 qfr[2][4];
  {
    const float* qb = q + ((size_t)n * SEQ + qt * 32 + m15) * EDIM + es * 128 + q4 * 8;
#pragma unroll
    for (int s = 0; s < 2; s++)
#pragma unroll
      for (int i = 0; i < 4; i++) {
        const float* src = qb + (size_t)s * 16 * EDIM + i * 32;
        float4 a = *reinterpret_cast<const float4*>(src);
        float4 b = *reinterpret_cast<const float4*>(src + 4);
        qfr[s][i] = cvt8(a, b);
      }
  }

  floatx4 oacc[2][4];                       // [strip][et_local], 32 regs (acc)
#pragma unroll
  for (int s = 0; s < 2; s++)
#pragma unroll
    for (int j = 0; j < 4; j++) oacc[s][j] = (floatx4){0.f, 0.f, 0.f, 0.f};

  uint32_t koff = ((uint32_t)(n * 128 + ks) * 16 + es * 4) * 512 + (uint32_t)lane * 8;
  uint32_t voff = ((uint32_t)(n * 64) * 32 + w * 4) * 512 + (uint32_t)lane * 8;

  // ---- K pipeline prologue: tile 0 fragments
  half8 kcur[4];
#pragma unroll
  for (int i = 0; i < 4; i++)
    kcur[i] = *reinterpret_cast<const half8*>(kf + koff + (uint32_t)i * 512);
  koff += 16384;                            // 2 rt * 16 est * 512

  block_sync_lds();                         // covers m/l init

  for (int t = 0; t < 64; t++) {
    // ---- S phase with current-tile K (already resident / in flight)
    floatx4 sacc[2];
    sacc[0] = (floatx4){0.f, 0.f, 0.f, 0.f};
    sacc[1] = (floatx4){0.f, 0.f, 0.f, 0.f};
    __builtin_amdgcn_s_setprio(1);
#pragma unroll
    for (int i = 0; i < 4; i++) {
      sacc[0] = __builtin_amdgcn_mfma_f32_16x16x32_f16(qfr[0][i], kcur[i], sacc[0], 0, 0, 0);
      sacc[1] = __builtin_amdgcn_mfma_f32_16x16x32_f16(qfr[1][i], kcur[i], sacc[1], 0, 0, 0);
    }
    __builtin_amdgcn_s_setprio(0);

    // ---- prefetch next-tile K + this-tile V: latency hides under
    // b1 + softmax + b2 (+ PV for K). t=63's K over-read lands in the
    // adjacent vf workspace region (in-bounds, never consumed).
    half8 knxt[4];
#pragma unroll
    for (int i = 0; i < 4; i++)
      knxt[i] = *reinterpret_cast<const half8*>(kf + koff + (uint32_t)i * 512);
    koff += 16384;

    half8 vfr[4];
#pragma unroll
    for (int j = 0; j < 4; j++)
      vfr[j] = *reinterpret_cast<const half8*>(vf + voff + (uint32_t)j * 512);
    voff += 16384;                          // 32 et * 512

    // write partials (C-layout: row = q4*4+r, col = m15)
#pragma unroll
    for (int s = 0; s < 2; s++)
#pragma unroll
      for (int r = 0; r < 4; r++)
        s_part[es][s * 16 + q4 * 4 + r][ks * 16 + m15] = sacc[s][r];
    block_sync_lds();                       // b1

    // ---- softmax: 32 rows x 16 threads, 2 cols each
    {
      const int r = tid >> 4, sub = tid & 15, c = sub * 2;
      float svx = s_part[0][r][c],     svy = s_part[0][r][c + 1];
#pragma unroll
      for (int pl = 1; pl < 4; pl++) { svx += s_part[pl][r][c]; svy += s_part[pl][r][c + 1]; }
      float mx = fmaxf(svx, svy);
#pragma unroll
      for (int o = 1; o < 16; o <<= 1) mx = fmaxf(mx, __shfl_xor(mx, o));
      const float mo = m_lds[r];
      const float mn = fmaxf(mo, mx);
      const float px = __expf(svx - mn), py = __expf(svy - mn);
      float rs = px + py;
#pragma unroll
      for (int o = 1; o < 16; o <<= 1) rs += __shfl_xor(rs, o);
      if (sub == 0) {
        const float al = __expf(mo - mn);
        a_lds[r] = al; m_lds[r] = mn; l_lds[r] = l_lds[r] * al + rs;
      }
      half2 ph; ph[0] = (_Float16)px; ph[1] = (_Float16)py;
      *reinterpret_cast<half2*>(&p_lds[r][c]) = ph;
    }
    block_sync_lds();                       // b2

    // ---- PV phase: P A-frags from LDS, rescale, MFMA (vfr already in flight)
    half8 pfr[2];
    pfr[0] = *reinterpret_cast<const half8*>(&p_lds[m15][q4 * 8]);
    pfr[1] = *reinterpret_cast<const half8*>(&p_lds[16 + m15][q4 * 8]);
    {
      floatx4 al0 = *reinterpret_cast<floatx4*>(&a_lds[q4 * 4]);
      floatx4 al1 = *reinterpret_cast<floatx4*>(&a_lds[16 + q4 * 4]);
#pragma unroll
      for (int j = 0; j < 4; j++) { oacc[0][j] *= al0; oacc[1][j] *= al1; }
    }
    __builtin_amdgcn_s_setprio(1);
#pragma unroll
    for (int j = 0; j < 4; j++) {
      oacc[0][j] = __builtin_amdgcn_mfma_f32_16x16x32_f16(pfr[0], vfr[j], oacc[0][j], 0, 0, 0);
      oacc[1][j] = __builtin_amdgcn_mfma_f32_16x16x32_f16(pfr[1], vfr[j], oacc[1][j], 0, 0, 0);
    }
    __builtin_amdgcn_s_setprio(0);

#pragma unroll
    for (int i = 0; i < 4; i++) kcur[i] = knxt[i];
  }

  // ---- epilogue: divide by l, store fp32 (l_lds final after last b2)
  const int q0 = qt * 32;
#pragma unroll
  for (int s = 0; s < 2; s++) {
    floatx4 lv = *reinterpret_cast<floatx4*>(&l_lds[s * 16 + q4 * 4]);
#pragma unroll
    for (int j = 0; j < 4; j++) {
      const int col = (w * 4 + j) * 16 + m15;
#pragma unroll
      for (int r = 0; r < 4; r++) {
        const int row = s * 16 + q4 * 4 + r;
        out[((size_t)n * SEQ + q0 + row) * EDIM + col] = oacc[s][j][r] / lv[r];
      }
    }
  }
}

// ---------------------------------------------------------------------------
// Fallback (ws too small): fp32 VALU attention, one block per query row.
// ---------------------------------------------------------------------------
__global__ void attn_fallback(const float* __restrict__ q, const float* __restrict__ k,
                              const float* __restrict__ v, float* __restrict__ out) {
  __shared__ float qrow[EDIM];
  __shared__ float sc[SEQ];
  __shared__ float red[16];
  const int tid = threadIdx.x;                    // 256
  const int n = blockIdx.x >> 11, qi = blockIdx.x & 2047;
  const int wv = tid >> 6, ln = tid & 63;
  const float* qp = q + ((size_t)n * SEQ + qi) * EDIM;
  for (int e = tid; e < EDIM; e += 256) qrow[e] = qp[e];
  __syncthreads();
  for (int kk = wv; kk < SEQ; kk += 4) {
    const float* kp = k + ((size_t)n * SEQ + kk) * EDIM;
    float s = 0.f;
    for (int e = ln; e < EDIM; e += 64) s = fmaf(qrow[e], kp[e], s);
    for (int o = 32; o > 0; o >>= 1) s += __shfl_down(s, o);
    if (ln == 0) sc[kk] = s;
  }
  __syncthreads();
  float mx = -3.0e38f;
  for (int kk = tid; kk < SEQ; kk += 256) mx = fmaxf(mx, sc[kk]);
  for (int o = 32; o > 0; o >>= 1) mx = fmaxf(mx, __shfl_down(mx, o));
  if (ln == 0) red[wv] = mx;
  __syncthreads();
  if (tid == 0) {
    float m2 = red[0];
    for (int i = 1; i < 4; i++) m2 = fmaxf(m2, red[i]);
    red[8] = m2;
  }
  __syncthreads();
  const float m = red[8];
  float ls = 0.f;
  for (int kk = tid; kk < SEQ; kk += 256) { float p = __expf(sc[kk] - m); sc[kk] = p; ls += p; }
  for (int o = 32; o > 0; o >>= 1) ls += __shfl_down(ls, o);
  if (ln == 0) red[wv] = ls;
  __syncthreads();
  if (tid == 0) { red[9] = red[0] + red[1] + red[2] + red[3]; }
  __syncthreads();
  const float linv = 1.f / red[9];
  for (int e = tid; e < EDIM; e += 256) {
    float acc = 0.f;
    const float* vp = v + ((size_t)n * SEQ) * EDIM + e;
    for (int kk = 0; kk < SEQ; kk++) acc = fmaf(sc[kk], vp[(size_t)kk * EDIM], acc);
    out[((size_t)n * SEQ + qi) * EDIM + e] = acc * linv;
  }
}

extern "C" void kernel_launch(void* const* d_in, const int* in_sizes, int n_in,
                              void* d_out, int out_size, void* d_ws, size_t ws_size,
                              hipStream_t stream) {
  const float* q = (const float*)d_in[0];
  const float* k = (const float*)d_in[1];
  const float* v = (const float*)d_in[2];
  float* out = (float*)d_out;
  const size_t need = 2 * NE * sizeof(_Float16);   // 33.6 MB (K + V frags)
  if (ws_size >= need) {
    _Float16* kf = (_Float16*)d_ws;
    _Float16* vf = kf + NE;
    make_frags<<<1024, 256, 0, stream>>>(k, v, kf, vf);
    attn_fused<<<512, 512, 0, stream>>>(q, kf, vf, out);
  } else {
    attn_fallback<<<16384, 256, 0, stream>>>(q, k, v, out);
  }
}